// Round 3
// baseline (222.116 us; speedup 1.0000x reference)
//
#include <hip/hip_runtime.h>
#include <hip/hip_bf16.h>
#include <math.h>

#define B_ 8
#define T_ 2048
#define C_ 1024
#define H_ 64
#define M_ (B_*T_)      // 16384

typedef __attribute__((ext_vector_type(8))) short short8;
typedef __attribute__((ext_vector_type(4))) float f32x4;
typedef unsigned int u32;

__device__ __forceinline__ unsigned short f2bf(float f) {
    u32 u = __builtin_bit_cast(u32, f);
    u += 0x7FFFu + ((u >> 16) & 1u);      // RNE
    return (unsigned short)(u >> 16);
}

// ---------------- Kernel 0: W -> bf16, transposed [n][k], q-scaled ----------------
__global__ __launch_bounds__(256) void wconv(
    const float* __restrict__ Wk, const float* __restrict__ Wq,
    const float* __restrict__ Wv, unsigned short* __restrict__ wb)
{
    int n = blockIdx.x;                    // 0..191
    const float* src = (n < 64) ? Wk : (n < 128 ? Wq : Wv);
    float sc = (n >= 64 && n < 128) ? 0.03125f : 1.0f;   // fold C^-0.5 into q
    int col = n & 63;
    for (int c = 0; c < 4; ++c) {
        int k = c * 256 + threadIdx.x;
        wb[(size_t)n * C_ + k] = f2bf(src[(size_t)k * H_ + col] * sc);
    }
}

// ---------------- Kernel 1: QKV GEMM, LDS-free ----------------
// Each wave: 16 rows x 48 cols. A-frags loaded directly from x (fp32->bf16 in regs),
// B-frags are contiguous 16B reads of pre-transposed W. No LDS, no barriers.
__global__ __launch_bounds__(256) void qkv_mm(
    const float* __restrict__ x, const unsigned short* __restrict__ wb,
    unsigned short* __restrict__ kb, unsigned short* __restrict__ qb,
    unsigned short* __restrict__ vT)
{
    const int tid = threadIdx.x;
    const int wid = tid >> 6;
    const int lane = tid & 63;
    const int lr = lane & 15;
    const int lg = lane >> 4;
    const int m0 = blockIdx.x * 16;

    const float* xrow = x + (size_t)(m0 + lr) * C_ + lg * 8;
    const unsigned short* wrow0 = wb + (size_t)(wid * 48 +  0 + lr) * C_ + lg * 8;
    const unsigned short* wrow1 = wb + (size_t)(wid * 48 + 16 + lr) * C_ + lg * 8;
    const unsigned short* wrow2 = wb + (size_t)(wid * 48 + 32 + lr) * C_ + lg * 8;

    f32x4 acc[3];
    for (int c = 0; c < 3; ++c) acc[c] = (f32x4){0.f, 0.f, 0.f, 0.f};

    #pragma unroll 4
    for (int t = 0; t < 32; ++t) {            // 32 k-chunks of 32
        int off = t * 32;
        float4 a0 = *reinterpret_cast<const float4*>(xrow + off);
        float4 a1 = *reinterpret_cast<const float4*>(xrow + off + 4);
        short8 af;
        af[0] = (short)f2bf(a0.x); af[1] = (short)f2bf(a0.y);
        af[2] = (short)f2bf(a0.z); af[3] = (short)f2bf(a0.w);
        af[4] = (short)f2bf(a1.x); af[5] = (short)f2bf(a1.y);
        af[6] = (short)f2bf(a1.z); af[7] = (short)f2bf(a1.w);
        short8 b0 = *reinterpret_cast<const short8*>(wrow0 + off);
        short8 b1 = *reinterpret_cast<const short8*>(wrow1 + off);
        short8 b2 = *reinterpret_cast<const short8*>(wrow2 + off);
        acc[0] = __builtin_amdgcn_mfma_f32_16x16x32_bf16(af, b0, acc[0], 0, 0, 0);
        acc[1] = __builtin_amdgcn_mfma_f32_16x16x32_bf16(af, b1, acc[1], 0, 0, 0);
        acc[2] = __builtin_amdgcn_mfma_f32_16x16x32_bf16(af, b2, acc[2], 0, 0, 0);
    }

    // epilogue: D layout col=lane&15, row=(lane>>4)*4+reg
    for (int ct = 0; ct < 3; ++ct) {
        int n = wid * 48 + ct * 16 + lr;
        int col = n & 63;
        for (int i = 0; i < 4; ++i) {
            int m = m0 + lg * 4 + i;
            unsigned short val = f2bf(acc[ct][i]);
            if (n < 64)       kb[(size_t)m * H_ + col] = val;
            else if (n < 128) qb[(size_t)m * H_ + col] = val;
            else              vT[((size_t)(m >> 11) * H_ + col) * T_ + (m & (T_ - 1))] = val;
        }
    }
}

// ---------------- Kernel 2: causal flash attention, split-KV across 4 waves ----------------
// Block = one 16-row q-tile; wave w takes kv steps w, w+4, ...; LDS merge at end.
__global__ __launch_bounds__(256) void attn3(
    const unsigned short* __restrict__ kb,
    const unsigned short* __restrict__ qb,
    const unsigned short* __restrict__ vT,
    float* __restrict__ out)
{
    __shared__ __align__(16) unsigned short Ps[4][16][72];
    __shared__ float Om[4][16][64];
    __shared__ float Mv[4][16], Lv[4][16], Fac[4][16], InvL[16];

    const int tid  = threadIdx.x;
    const int wid  = tid >> 6;
    const int lane = tid & 63;
    const int lr   = lane & 15;
    const int lg   = lane >> 4;
    const int b    = blockIdx.y;
    const int bx   = blockIdx.x;
    const int tile = (bx & 1) ? (127 - (bx >> 1)) : (bx >> 1);  // pair big+small
    const int q0   = tile * 16;
    const int nsteps = (tile >> 2) + 1;
    const size_t base = (size_t)b * T_ * H_;
    const unsigned short* vTb = vT + (size_t)b * H_ * T_;

    short8 qf[2];
    for (int kc = 0; kc < 2; ++kc)
        qf[kc] = *reinterpret_cast<const short8*>(
            qb + base + (size_t)(q0 + lr) * H_ + kc * 32 + lg * 8);

    f32x4 o[4];
    float mrun[4], lrun[4];
    for (int dt = 0; dt < 4; ++dt) o[dt] = (f32x4){0.f, 0.f, 0.f, 0.f};
    for (int i = 0; i < 4; ++i) { mrun[i] = -INFINITY; lrun[i] = 0.f; }

    for (int s = wid; s < nsteps; s += 4) {
        const int kv0 = s * 64;

        // S = Q K^T  (16 q-rows x 64 keys), K frags direct from L2
        f32x4 sv4[4];
        for (int kt = 0; kt < 4; ++kt) sv4[kt] = (f32x4){0.f, 0.f, 0.f, 0.f};
        for (int kc = 0; kc < 2; ++kc) {
            for (int kt = 0; kt < 4; ++kt) {
                short8 kf = *reinterpret_cast<const short8*>(
                    kb + base + (size_t)(kv0 + kt * 16 + lr) * H_ + kc * 32 + lg * 8);
                sv4[kt] = __builtin_amdgcn_mfma_f32_16x16x32_bf16(qf[kc], kf, sv4[kt], 0, 0, 0);
            }
        }

        // causal mask + online softmax (lane holds rows lg*4+i, key col = lr per kt-tile)
        for (int i = 0; i < 4; ++i) {
            int row = q0 + lg * 4 + i;
            float sv[4];
            float mx = -INFINITY;
            for (int kt = 0; kt < 4; ++kt) {
                int key = kv0 + kt * 16 + lr;
                float v = (key <= row) ? sv4[kt][i] : -INFINITY;
                sv[kt] = v;
                mx = fmaxf(mx, v);
            }
            for (int d = 8; d; d >>= 1) mx = fmaxf(mx, __shfl_xor(mx, d));
            float mn  = fmaxf(mrun[i], mx);
            float fac = __expf(mrun[i] - mn);
            float rs  = 0.f;
            for (int kt = 0; kt < 4; ++kt) {
                float p = __expf(sv[kt] - mn);
                rs += p;
                Ps[wid][lg * 4 + i][kt * 16 + lr] = f2bf(p);
            }
            for (int d = 8; d; d >>= 1) rs += __shfl_xor(rs, d);
            lrun[i] = lrun[i] * fac + rs;
            mrun[i] = mn;
            for (int dt = 0; dt < 4; ++dt)
                o[dt][i] *= fac;
        }

        // O += P * V, V^T frags contiguous 16B
        for (int kc = 0; kc < 2; ++kc) {
            short8 pf = *reinterpret_cast<const short8*>(&Ps[wid][lr][kc * 32 + lg * 8]);
            for (int dt = 0; dt < 4; ++dt) {
                short8 vf = *reinterpret_cast<const short8*>(
                    vTb + (size_t)(dt * 16 + lr) * T_ + kv0 + kc * 32 + lg * 8);
                o[dt] = __builtin_amdgcn_mfma_f32_16x16x32_bf16(pf, vf, o[dt], 0, 0, 0);
            }
        }
    }

    // ---- merge the 4 per-wave partial states ----
    for (int dt = 0; dt < 4; ++dt)
        for (int i = 0; i < 4; ++i)
            Om[wid][lg * 4 + i][dt * 16 + lr] = o[dt][i];
    if (lr == 0)
        for (int i = 0; i < 4; ++i) {
            Mv[wid][lg * 4 + i] = mrun[i];
            Lv[wid][lg * 4 + i] = lrun[i];
        }
    __syncthreads();
    if (tid < 16) {
        float M = Mv[0][tid];
        for (int w = 1; w < 4; ++w) M = fmaxf(M, Mv[w][tid]);
        float L = 0.f;
        for (int w = 0; w < 4; ++w) {
            float f = __expf(Mv[w][tid] - M);
            Fac[w][tid] = f;
            L += Lv[w][tid] * f;
        }
        InvL[tid] = 1.0f / L;
    }
    __syncthreads();
    for (int e = 0; e < 4; ++e) {
        int idx = e * 256 + tid;
        int row = idx >> 6, d = idx & 63;
        float v = 0.f;
        for (int w = 0; w < 4; ++w) v += Om[w][row][d] * Fac[w][row];
        out[base + (size_t)(q0 + row) * H_ + d] = v * InvL[row];
    }
}

extern "C" void kernel_launch(void* const* d_in, const int* in_sizes, int n_in,
                              void* d_out, int out_size, void* d_ws, size_t ws_size,
                              hipStream_t stream) {
    const float* x  = (const float*)d_in[0];
    const float* Wk = (const float*)d_in[1];
    const float* Wq = (const float*)d_in[2];
    const float* Wv = (const float*)d_in[3];
    float* out = (float*)d_out;

    unsigned short* kb = (unsigned short*)d_ws;              // 1 M elems
    unsigned short* qb = kb + (size_t)M_ * H_;               // 1 M elems
    unsigned short* vT = qb + (size_t)M_ * H_;               // 1 M elems ([b][d][t])
    unsigned short* wb = vT + (size_t)M_ * H_;               // 192*1024 elems

    wconv<<<192, 256, 0, stream>>>(Wk, Wq, Wv, wb);
    qkv_mm<<<M_ / 16, 256, 0, stream>>>(x, wb, kb, qb, vT);
    attn3<<<dim3(128, B_), 256, 0, stream>>>(kb, qb, vT, out);
}

// Round 4
// 179.503 us; speedup vs baseline: 1.2374x; 1.2374x over previous
//
#include <hip/hip_runtime.h>
#include <hip/hip_bf16.h>
#include <math.h>

#define B_ 8
#define T_ 2048
#define C_ 1024
#define H_ 64
#define M_ (B_*T_)      // 16384

typedef __attribute__((ext_vector_type(8))) short short8;
typedef __attribute__((ext_vector_type(4))) float f32x4;
typedef unsigned int u32;

__device__ __forceinline__ unsigned short f2bf(float f) {
    u32 u = __builtin_bit_cast(u32, f);
    u += 0x7FFFu + ((u >> 16) & 1u);      // RNE
    return (unsigned short)(u >> 16);
}

__device__ __forceinline__ void gl2lds16(const void* g, void* l) {
    __builtin_amdgcn_global_load_lds(
        (const __attribute__((address_space(1))) u32*)g,
        (__attribute__((address_space(3))) u32*)l, 16, 0, 0);
}

// ---------------- Kernel 0: W -> bf16, transposed [n][k], q-scaled, XOR-swizzled ----------------
// wb row n (2048 B = 16 chunks of 128 B): element k sits in chunk k>>6 at byte
// ((k&63)*2) ^ ((n&7)<<4). Swizzle is baked at the SOURCE so qkv_mm can stage
// linearly with global_load_lds and XOR only on the ds_read side.
__global__ __launch_bounds__(256) void wconv(
    const float* __restrict__ Wk, const float* __restrict__ Wq,
    const float* __restrict__ Wv, unsigned short* __restrict__ wb)
{
    __shared__ unsigned short lt[64][64];          // [n][k_local]
    const int mat = blockIdx.x >> 4;               // 0:k 1:q 2:v
    const int k0  = (blockIdx.x & 15) * 64;
    const float* src = (mat == 0) ? Wk : (mat == 1 ? Wq : Wv);
    const float sc = (mat == 1) ? 0.03125f : 1.0f; // fold C^-0.5 into q
    const int tid = threadIdx.x;

    for (int it = 0; it < 16; ++it) {
        int idx = it * 256 + tid;                  // 0..4095
        int r = idx >> 6, cn = idx & 63;           // r=k_local, cn=n_local
        lt[cn][r] = f2bf(src[(size_t)(k0 + r) * H_ + cn] * sc);
    }
    __syncthreads();
    for (int g = 0; g < 2; ++g) {
        int n  = g * 32 + (tid >> 3);
        int kp = tid & 7;
        int ng = mat * 64 + n;
        short8 v = *reinterpret_cast<const short8*>(&lt[n][kp * 8]);
        char* dst = (char*)wb + (size_t)ng * 2048 + (k0 >> 6) * 128
                  + ((kp * 16) ^ ((ng & 7) << 4));
        *reinterpret_cast<short8*>(dst) = v;
    }
}

// ---------------- Kernel 1: QKV GEMM ----------------
// BM=64 (4 waves x 16 rows), BN=96 (2 blocks cover N=192), BK=64.
// W: global_load_lds double-buffered (linear LDS, swizzled content).
// X: per-lane direct global loads = A fragments, prefetched one step ahead.
__global__ __launch_bounds__(256, 2) void qkv_mm(
    const float* __restrict__ x, const unsigned short* __restrict__ wb,
    unsigned short* __restrict__ kb, unsigned short* __restrict__ qb,
    unsigned short* __restrict__ vT)
{
    __shared__ __align__(16) unsigned short Ws[2][96 * 64];   // 24 KB

    const int tid  = threadIdx.x;
    const int wid  = tid >> 6;
    const int lane = tid & 63;
    const int lr   = lane & 15;
    const int lg   = lane >> 4;
    const int mt   = blockIdx.x >> 1;
    const int bn   = blockIdx.x & 1;
    const int m0   = mt * 64;
    const int n0   = bn * 96;

    const float* xrow = x + (size_t)(m0 + wid * 16 + lr) * C_ + lg * 8;

    f32x4 acc[6];
    for (int c = 0; c < 6; ++c) acc[c] = (f32x4){0.f, 0.f, 0.f, 0.f};

    // prologue: x(0) into regs, W-tile(0) into buf0
    float4 xa = *reinterpret_cast<const float4*>(xrow);
    float4 xb2 = *reinterpret_cast<const float4*>(xrow + 4);
    float4 xc = *reinterpret_cast<const float4*>(xrow + 32);
    float4 xd = *reinterpret_cast<const float4*>(xrow + 36);
    for (int p = 0; p < 3; ++p) {
        int c = p * 256 + tid;                    // 0..767
        gl2lds16((const char*)wb + (size_t)(n0 + (c >> 3)) * 2048 + (c & 7) * 16,
                 (char*)&Ws[0][0] + c * 16);
    }

    for (int t = 0; t < 16; ++t) {
        __syncthreads();   // drains stage(t) + x(t); prev-buf readers done
        float4 na, nb, nc, nd;
        if (t < 15) {
            const float* xn = xrow + (t + 1) * 64;
            na = *reinterpret_cast<const float4*>(xn);
            nb = *reinterpret_cast<const float4*>(xn + 4);
            nc = *reinterpret_cast<const float4*>(xn + 32);
            nd = *reinterpret_cast<const float4*>(xn + 36);
            int buf = (t + 1) & 1;
            for (int p = 0; p < 3; ++p) {
                int c = p * 256 + tid;
                gl2lds16((const char*)wb + (size_t)(n0 + (c >> 3)) * 2048
                             + (size_t)(t + 1) * 128 + (c & 7) * 16,
                         (char*)&Ws[buf][0] + c * 16);
            }
        }

        short8 af0, af1;
        af0[0] = (short)f2bf(xa.x); af0[1] = (short)f2bf(xa.y);
        af0[2] = (short)f2bf(xa.z); af0[3] = (short)f2bf(xa.w);
        af0[4] = (short)f2bf(xb2.x); af0[5] = (short)f2bf(xb2.y);
        af0[6] = (short)f2bf(xb2.z); af0[7] = (short)f2bf(xb2.w);
        af1[0] = (short)f2bf(xc.x); af1[1] = (short)f2bf(xc.y);
        af1[2] = (short)f2bf(xc.z); af1[3] = (short)f2bf(xc.w);
        af1[4] = (short)f2bf(xd.x); af1[5] = (short)f2bf(xd.y);
        af1[6] = (short)f2bf(xd.z); af1[7] = (short)f2bf(xd.w);

        const char* wbuf = (const char*)&Ws[t & 1][0];
        #pragma unroll
        for (int kc = 0; kc < 2; ++kc) {
            short8 afc = kc ? af1 : af0;
            #pragma unroll
            for (int ct = 0; ct < 6; ++ct) {
                int n = ct * 16 + lr;
                short8 bf = *reinterpret_cast<const short8*>(
                    wbuf + n * 128 + ((kc * 64 + lg * 16) ^ ((n & 7) << 4)));
                acc[ct] = __builtin_amdgcn_mfma_f32_16x16x32_bf16(afc, bf, acc[ct], 0, 0, 0);
            }
        }
        xa = na; xb2 = nb; xc = nc; xd = nd;
    }

    // epilogue: D layout col=lane&15, row=(lane>>4)*4+reg
    for (int ct = 0; ct < 6; ++ct) {
        int ng = n0 + ct * 16 + lr;
        int col = ng & 63;
        for (int i = 0; i < 4; ++i) {
            int m = m0 + wid * 16 + lg * 4 + i;
            unsigned short val = f2bf(acc[ct][i]);
            if (ng < 64)       kb[(size_t)m * H_ + col] = val;
            else if (ng < 128) qb[(size_t)m * H_ + col] = val;
            else               vT[((size_t)(m >> 11) * H_ + col) * T_ + (m & (T_ - 1))] = val;
        }
    }
}

// ---------------- Kernel 2: causal flash attention, split-KV across 4 waves ----------------
__global__ __launch_bounds__(256, 2) void attn4(
    const unsigned short* __restrict__ kb,
    const unsigned short* __restrict__ qb,
    const unsigned short* __restrict__ vT,
    float* __restrict__ out)
{
    __shared__ __align__(16) unsigned short Ps[4][16][72];
    __shared__ float Om[4][16][64];
    __shared__ float Mv[4][16], Lv[4][16], Fac[4][16], InvL[16];

    const int tid  = threadIdx.x;
    const int wid  = tid >> 6;
    const int lane = tid & 63;
    const int lr   = lane & 15;
    const int lg   = lane >> 4;
    const int b    = blockIdx.y;
    const int bx   = blockIdx.x;
    const int tile = (bx & 1) ? (127 - (bx >> 1)) : (bx >> 1);  // mix big+small
    const int q0   = tile * 16;
    const int nsteps = (tile >> 2) + 1;
    const size_t base = (size_t)b * T_ * H_;
    const unsigned short* vTb = vT + (size_t)b * H_ * T_;

    short8 qf[2];
    #pragma unroll
    for (int kc = 0; kc < 2; ++kc)
        qf[kc] = *reinterpret_cast<const short8*>(
            qb + base + (size_t)(q0 + lr) * H_ + kc * 32 + lg * 8);

    f32x4 o[4];
    float mrun[4], lrun[4];
    for (int dt = 0; dt < 4; ++dt) o[dt] = (f32x4){0.f, 0.f, 0.f, 0.f};
    for (int i = 0; i < 4; ++i) { mrun[i] = -INFINITY; lrun[i] = 0.f; }

    for (int s = wid; s < nsteps; s += 4) {
        const int kv0 = s * 64;

        // batch-issue all K fragment loads
        short8 kf[2][4];
        #pragma unroll
        for (int kc = 0; kc < 2; ++kc)
            #pragma unroll
            for (int kt = 0; kt < 4; ++kt)
                kf[kc][kt] = *reinterpret_cast<const short8*>(
                    kb + base + (size_t)(kv0 + kt * 16 + lr) * H_ + kc * 32 + lg * 8);

        f32x4 sv4[4];
        for (int kt = 0; kt < 4; ++kt) sv4[kt] = (f32x4){0.f, 0.f, 0.f, 0.f};
        #pragma unroll
        for (int kc = 0; kc < 2; ++kc)
            #pragma unroll
            for (int kt = 0; kt < 4; ++kt)
                sv4[kt] = __builtin_amdgcn_mfma_f32_16x16x32_bf16(qf[kc], kf[kc][kt], sv4[kt], 0, 0, 0);

        // issue V loads now; latency hides under softmax
        short8 vf[2][4];
        #pragma unroll
        for (int kc = 0; kc < 2; ++kc)
            #pragma unroll
            for (int dt = 0; dt < 4; ++dt)
                vf[kc][dt] = *reinterpret_cast<const short8*>(
                    vTb + (size_t)(dt * 16 + lr) * T_ + kv0 + kc * 32 + lg * 8);

        const bool need_mask = (s == nsteps - 1);   // only diagonal tile masks

        for (int i = 0; i < 4; ++i) {
            int row = q0 + lg * 4 + i;
            float sv[4];
            float mx = -INFINITY;
            if (need_mask) {
                for (int kt = 0; kt < 4; ++kt) {
                    int key = kv0 + kt * 16 + lr;
                    float v = (key <= row) ? sv4[kt][i] : -INFINITY;
                    sv[kt] = v;
                    mx = fmaxf(mx, v);
                }
            } else {
                for (int kt = 0; kt < 4; ++kt) {
                    sv[kt] = sv4[kt][i];
                    mx = fmaxf(mx, sv[kt]);
                }
            }
            for (int d = 8; d; d >>= 1) mx = fmaxf(mx, __shfl_xor(mx, d));
            float mn  = fmaxf(mrun[i], mx);
            float fac = __expf(mrun[i] - mn);
            float rs  = 0.f;
            for (int kt = 0; kt < 4; ++kt) {
                float p = __expf(sv[kt] - mn);
                rs += p;
                Ps[wid][lg * 4 + i][kt * 16 + lr] = f2bf(p);
            }
            for (int d = 8; d; d >>= 1) rs += __shfl_xor(rs, d);
            lrun[i] = lrun[i] * fac + rs;
            mrun[i] = mn;
            for (int dt = 0; dt < 4; ++dt)
                o[dt][i] *= fac;
        }

        // O += P * V
        #pragma unroll
        for (int kc = 0; kc < 2; ++kc) {
            short8 pf = *reinterpret_cast<const short8*>(&Ps[wid][lr][kc * 32 + lg * 8]);
            #pragma unroll
            for (int dt = 0; dt < 4; ++dt)
                o[dt] = __builtin_amdgcn_mfma_f32_16x16x32_bf16(pf, vf[kc][dt], o[dt], 0, 0, 0);
        }
    }

    // ---- merge the 4 per-wave partial states ----
    for (int dt = 0; dt < 4; ++dt)
        for (int i = 0; i < 4; ++i)
            Om[wid][lg * 4 + i][dt * 16 + lr] = o[dt][i];
    if (lr == 0)
        for (int i = 0; i < 4; ++i) {
            Mv[wid][lg * 4 + i] = mrun[i];
            Lv[wid][lg * 4 + i] = lrun[i];
        }
    __syncthreads();
    if (tid < 16) {
        float M = Mv[0][tid];
        for (int w = 1; w < 4; ++w) M = fmaxf(M, Mv[w][tid]);
        float L = 0.f;
        for (int w = 0; w < 4; ++w) {
            float f = __expf(Mv[w][tid] - M);
            Fac[w][tid] = f;
            L += Lv[w][tid] * f;
        }
        InvL[tid] = 1.0f / L;
    }
    __syncthreads();
    for (int e = 0; e < 4; ++e) {
        int idx = e * 256 + tid;
        int row = idx >> 6, d = idx & 63;
        float v = 0.f;
        for (int w = 0; w < 4; ++w) v += Om[w][row][d] * Fac[w][row];
        out[base + (size_t)(q0 + row) * H_ + d] = v * InvL[row];
    }
}

extern "C" void kernel_launch(void* const* d_in, const int* in_sizes, int n_in,
                              void* d_out, int out_size, void* d_ws, size_t ws_size,
                              hipStream_t stream) {
    const float* x  = (const float*)d_in[0];
    const float* Wk = (const float*)d_in[1];
    const float* Wq = (const float*)d_in[2];
    const float* Wv = (const float*)d_in[3];
    float* out = (float*)d_out;

    unsigned short* kb = (unsigned short*)d_ws;              // 1 M elems
    unsigned short* qb = kb + (size_t)M_ * H_;               // 1 M elems
    unsigned short* vT = qb + (size_t)M_ * H_;               // 1 M elems ([b][d][t])
    unsigned short* wb = vT + (size_t)M_ * H_;               // 192*1024 elems

    wconv<<<48, 256, 0, stream>>>(Wk, Wq, Wv, wb);
    qkv_mm<<<512, 256, 0, stream>>>(x, wb, kb, qb, vT);
    attn4<<<dim3(128, B_), 256, 0, stream>>>(kb, qb, vT, out);
}